// Round 6
// baseline (177.533 us; speedup 1.0000x reference)
//
#include <hip/hip_runtime.h>
#include <hip/hip_bf16.h>
#include <stdint.h>

typedef __attribute__((ext_vector_type(8))) short bf16x8;
typedef __attribute__((ext_vector_type(4))) float f32x4;
typedef __attribute__((ext_vector_type(4))) short short4v;
typedef __attribute__((ext_vector_type(2))) unsigned u32x2;

#define SCALE2 0.18033688011112042f  /* (1/8) * log2(e) */

__device__ __forceinline__ short f2b(float f) {
  union { float f; unsigned u; } un; un.f = f;
  unsigned r = un.u + 0x7FFFu + ((un.u >> 16) & 1u);
  return (short)(r >> 16);
}

// async global->LDS, 16B per lane; LDS dest is wave-uniform base + lane*16
#define GLDS(GP, LP) __builtin_amdgcn_global_load_lds( \
    (__attribute__((address_space(1))) void*)(GP), \
    (__attribute__((address_space(3))) void*)(LP), 16, 0, 0)

// ---------------- fused f32 -> bf16 conversion ----------------
struct CvtTab { const float* s[12]; short* d[12]; };

__global__ void cvt_all(CvtTab tab) {
  int chunk = blockIdx.x >> 10;
  int off = (blockIdx.x & 1023) * 256 + threadIdx.x;
  float4 v = *((const float4*)tab.s[chunk] + off);
  short4v o;
  o[0] = f2b(v.x); o[1] = f2b(v.y); o[2] = f2b(v.z); o[3] = f2b(v.w);
  *((short4v*)tab.d[chunk] + off) = o;
}

// ---------------- 128x128 bf16 GEMM core, K=1024, 2-phase dbuf ----------------
__device__ __forceinline__ void gemm_core128(
    const short* __restrict__ A, const short* __restrict__ W,
    int tile_m, int tile_n, short* lds, f32x4 acc[4][4])
{
  const int tid = threadIdx.x;
  const int wave = tid >> 6, lane = tid & 63;
  const int wr = wave >> 1, wc = wave & 1;
  const int q15 = lane & 15, q4 = lane >> 4;
  const int rl = lane >> 3;
  const int cswz = ((lane & 7) * 16) ^ (rl << 4);

#pragma unroll
  for (int i = 0; i < 4; ++i)
#pragma unroll
    for (int j = 0; j < 4; ++j) acc[i][j] = (f32x4){0.f, 0.f, 0.f, 0.f};

  auto stage = [&](int buf, int k0) {
    short* As = lds + buf * 16384;
    short* Bs = As + 8192;
#pragma unroll
    for (int s = 0; s < 4; ++s) {
      int ia = wave * 4 + s;
      int row = ia * 8 + rl;
      GLDS(A + (size_t)(tile_m + row) * 1024 + k0 + (cswz >> 1), (char*)As + ia * 1024);
      GLDS(W + (size_t)(tile_n + row) * 1024 + k0 + (cswz >> 1), (char*)Bs + ia * 1024);
    }
  };

  stage(0, 0);
  __syncthreads();
  for (int t = 0; t < 16; ++t) {
    const int cur = t & 1;
    if (t < 15) stage(cur ^ 1, (t + 1) * 64);
    const short* As = lds + cur * 16384;
    const short* Bs = As + 8192;
#pragma unroll
    for (int kk = 0; kk < 2; ++kk) {
      const int kbyte = kk * 64 + q4 * 16;
      const int rswz = (q15 & 7) << 4;
      bf16x8 af[4], bfr[4];
#pragma unroll
      for (int i = 0; i < 4; ++i)
        af[i] = *(const bf16x8*)((const char*)As + (wr * 64 + i * 16 + q15) * 128 + (kbyte ^ rswz));
#pragma unroll
      for (int j = 0; j < 4; ++j)
        bfr[j] = *(const bf16x8*)((const char*)Bs + (wc * 64 + j * 16 + q15) * 128 + (kbyte ^ rswz));
#pragma unroll
      for (int i = 0; i < 4; ++i)
#pragma unroll
        for (int j = 0; j < 4; ++j)
          acc[i][j] = __builtin_amdgcn_mfma_f32_16x16x32_bf16(af[i], bfr[j], acc[i][j], 0, 0, 0);
    }
    __syncthreads();
  }
}

// ---------------- stacked QKVP projection GEMM ----------------
__global__ __launch_bounds__(256)
void gemm_qkvp(const short* __restrict__ q_in, const short* __restrict__ k_in,
               const short* __restrict__ v_in, const short* __restrict__ p_in,
               const short* __restrict__ wq, const short* __restrict__ wk,
               const short* __restrict__ wv, const short* __restrict__ wp,
               const float* __restrict__ bq, const float* __restrict__ bk,
               const float* __restrict__ bv, const float* __restrict__ bp,
               const float* __restrict__ ub, const float* __restrict__ vb,
               short* __restrict__ qu, short* __restrict__ qv,
               short* __restrict__ kx, short* __restrict__ vtp, short* __restrict__ pp)
{
  __shared__ __align__(16) short lds[32768];
  const int n = blockIdx.x;
  const int by = n & 7;
  const int bx = n >> 3;
  const short* A; const short* W; const float* bias; int tm, mode;
  if (bx < 16)      { A = q_in; W = wq; bias = bq; tm = bx;      mode = 0; }
  else if (bx < 32) { A = k_in; W = wk; bias = bk; tm = bx - 16; mode = 1; }
  else if (bx < 48) { A = v_in; W = wv; bias = bv; tm = bx - 32; mode = 2; }
  else              { A = p_in; W = wp; bias = bp; tm = bx - 48; mode = 3; }

  f32x4 acc[4][4];
  gemm_core128(A, W, tm * 128, by * 128, lds, acc);

  const int lane = threadIdx.x & 63, wave = threadIdx.x >> 6;
  const int wr = wave >> 1, wc = wave & 1, q15 = lane & 15, q4 = lane >> 4;
#pragma unroll
  for (int i = 0; i < 4; ++i)
#pragma unroll
    for (int j = 0; j < 4; ++j)
#pragma unroll
      for (int r = 0; r < 4; ++r) {
        int m = tm * 128 + wr * 64 + i * 16 + q4 * 4 + r;
        int nn = by * 128 + wc * 64 + j * 16 + q15;
        float v = acc[i][j][r] + bias[nn];
        int bb = m >> 10, t = m & 1023, hh = nn >> 6, d = nn & 63;
        if (mode == 0) {
          size_t o = ((size_t)(bb * 16 + hh) * 1024 + t) * 64 + d;
          qu[o] = f2b((v + ub[nn]) * SCALE2);   // pre-scale: scores come out in log2 units
          qv[o] = f2b((v + vb[nn]) * SCALE2);
        } else if (mode == 1) {
          kx[((size_t)(bb * 16 + hh) * 1024 + t) * 64 + d] = f2b(v);
        } else if (mode == 2) {
          vtp[((size_t)(bb * 16 + hh) * 64 + d) * 1024 + t] = f2b(v);
        } else {
          pp[((size_t)hh * 1024 + m) * 64 + d] = f2b(v);
        }
      }
}

// ---------------- output GEMM, 128x64 tiles (256 blocks), f32 out ----------------
__global__ __launch_bounds__(256)
void gemm_out(const short* __restrict__ X, const short* __restrict__ W,
              const float* __restrict__ bo, float* __restrict__ out)
{
  __shared__ __align__(16) short lds[24576];
  const int n = blockIdx.x;
  const int bxm = (n >> 3) & 15;
  const int byn = ((n & 7) << 1) | (n >> 7);
  const int tile_m = bxm * 128, tile_n = byn * 64;

  const int tid = threadIdx.x;
  const int wave = tid >> 6, lane = tid & 63;
  const int wr = wave >> 1, wc = wave & 1;
  const int q15 = lane & 15, q4 = lane >> 4;
  const int rl = lane >> 3;
  const int cswz = ((lane & 7) * 16) ^ (rl << 4);

  f32x4 acc[4][2];
#pragma unroll
  for (int i = 0; i < 4; ++i)
#pragma unroll
    for (int j = 0; j < 2; ++j) acc[i][j] = (f32x4){0.f, 0.f, 0.f, 0.f};

  auto stage = [&](int buf, int k0) {
    short* As = lds + buf * 12288;
    short* Bs = As + 8192;
#pragma unroll
    for (int s = 0; s < 6; ++s) {
      int idx = wave * 6 + s;
      if (idx < 16) {
        int row = idx * 8 + rl;
        GLDS(X + (size_t)(tile_m + row) * 1024 + k0 + (cswz >> 1), (char*)As + idx * 1024);
      } else {
        int i2 = idx - 16;
        int row = i2 * 8 + rl;
        GLDS(W + (size_t)(tile_n + row) * 1024 + k0 + (cswz >> 1), (char*)Bs + i2 * 1024);
      }
    }
  };

  stage(0, 0);
  __syncthreads();
  for (int t = 0; t < 16; ++t) {
    const int cur = t & 1;
    if (t < 15) stage(cur ^ 1, (t + 1) * 64);
    const short* As = lds + cur * 12288;
    const short* Bs = As + 8192;
#pragma unroll
    for (int kk = 0; kk < 2; ++kk) {
      const int kbyte = kk * 64 + q4 * 16;
      const int rswz = (q15 & 7) << 4;
      bf16x8 af[4], bfr[2];
#pragma unroll
      for (int i = 0; i < 4; ++i)
        af[i] = *(const bf16x8*)((const char*)As + (wr * 64 + i * 16 + q15) * 128 + (kbyte ^ rswz));
#pragma unroll
      for (int j = 0; j < 2; ++j)
        bfr[j] = *(const bf16x8*)((const char*)Bs + (wc * 32 + j * 16 + q15) * 128 + (kbyte ^ rswz));
#pragma unroll
      for (int i = 0; i < 4; ++i)
#pragma unroll
        for (int j = 0; j < 2; ++j)
          acc[i][j] = __builtin_amdgcn_mfma_f32_16x16x32_bf16(af[i], bfr[j], acc[i][j], 0, 0, 0);
    }
    __syncthreads();
  }

#pragma unroll
  for (int i = 0; i < 4; ++i)
#pragma unroll
    for (int j = 0; j < 2; ++j)
#pragma unroll
      for (int r = 0; r < 4; ++r) {
        int m = tile_m + wr * 64 + i * 16 + q4 * 4 + r;
        int nn = tile_n + wc * 32 + j * 16 + q15;
        out[(size_t)m * 1024 + nn] = acc[i][j][r] + bo[nn];
      }
}

// ---------------- fused rel-pos flash attention: barrier-free 1-wave blocks ----------------
// Each block = one wave owning 16 t-rows x 512 s. K/V/p fragments read directly
// from global (L2-resident with XCD swizzle); only per-wave Bl/Pl scratch in LDS.
__global__ __launch_bounds__(64, 6)
void attn_kernel(const short* __restrict__ qu, const short* __restrict__ qv,
                 const short* __restrict__ kmat, const short* __restrict__ vt,
                 const short* __restrict__ p,
                 float* __restrict__ Opart, float* __restrict__ larr)
{
  __shared__ __align__(16) short Bl[2048];   // 16 t-rows x 128 j-cols (circular), swizzled
  __shared__ __align__(16) short Pl[1024];   // 16 t-rows x 64 s-cols, swizzled

  // XCD swizzle: 512 consecutive work items per XCD (shared K/V/p per (h,z) group)
  const int nB = blockIdx.x;
  const int o = (nB & 7) * 512 + (nB >> 3);
  const int tb = (o & 63) * 16;        // t-row base (16-aligned)
  const int h = (o >> 6) & 15;
  const int z = o >> 10;
  const int b = z >> 1, sh = z & 1;

  const int lane = threadIdx.x;
  const int q15 = lane & 15, q4 = lane >> 4;
  const size_t bh = (size_t)(b * 16 + h);
  const short* pW = p + (size_t)h * 65536;
  const short* kB = kmat + bh * 65536;
  const short* vB = vt + bh * 65536;
  const int rswz = (q15 & 7) << 4;
  const int blrow = q15 * 256;
  const int plrow = q15 * 128;

  bf16x8 quf[2], qvf[2];
  {
    size_t base = (bh * 1024 + tb + q15) * 64 + q4 * 8;
    quf[0] = *(const bf16x8*)(qu + base);
    quf[1] = *(const bf16x8*)(qu + base + 32);
    qvf[0] = *(const bf16x8*)(qv + base);
    qvf[1] = *(const bf16x8*)(qv + base + 32);
  }
  bf16x8 ones;
#pragma unroll
  for (int i = 0; i < 8; ++i) ones[i] = (short)0x3F80;  // bf16 1.0

  f32x4 acco[4], accl;
#pragma unroll
  for (int g = 0; g < 4; ++g) acco[g] = (f32x4){0.f, 0.f, 0.f, 0.f};
  accl = (f32x4){0.f, 0.f, 0.f, 0.f};

  int live0 = -1, live1 = -1;

  // refill: BD window rows j in [base, base+64); lane holds j=base+16g+4q4+r at t-col q15
  auto refill = [&](int base) {
    f32x4 bacc[4];
#pragma unroll
    for (int g = 0; g < 4; ++g) bacc[g] = (f32x4){0.f, 0.f, 0.f, 0.f};
#pragma unroll
    for (int kc = 0; kc < 2; ++kc) {
      const int kof = kc * 32 + q4 * 8;
#pragma unroll
      for (int g = 0; g < 4; ++g) {
        bf16x8 pf = *(const bf16x8*)(pW + (size_t)(base + g * 16 + q15) * 64 + kof);
        bacc[g] = __builtin_amdgcn_mfma_f32_16x16x32_bf16(pf, qvf[kc], bacc[g], 0, 0, 0);
      }
    }
    const int pbase = base & 127;
#pragma unroll
    for (int g = 0; g < 4; ++g) {
      unsigned a0 = __float_as_uint(bacc[g][0]); a0 = a0 + 0x7FFFu + ((a0 >> 16) & 1u);
      unsigned a1 = __float_as_uint(bacc[g][1]); a1 = a1 + 0x7FFFu + ((a1 >> 16) & 1u);
      unsigned a2 = __float_as_uint(bacc[g][2]); a2 = a2 + 0x7FFFu + ((a2 >> 16) & 1u);
      unsigned a3 = __float_as_uint(bacc[g][3]); a3 = a3 + 0x7FFFu + ((a3 >> 16) & 1u);
      u32x2 pk;
      pk[0] = (a0 >> 16) | (a1 & 0xFFFF0000u);
      pk[1] = (a2 >> 16) | (a3 & 0xFFFF0000u);
      int inrow = (pbase + 16 * g + 4 * q4) * 2;
      *(u32x2*)((char*)Bl + blrow + (inrow ^ rswz)) = pk;
    }
  };

  auto ensure = [&](int base) {
    if ((base >> 6) & 1) { if (live1 != base) { refill(base); live1 = base; } }
    else                 { if (live0 != base) { refill(base); live0 = base; } }
  };

  const int sbeg = sh * 512;
  for (int s0 = sbeg; s0 < sbeg + 512; s0 += 64) {
    const int D = tb - s0;   // t-s offset, multiple of 16

    // window maintenance: j = 1023-|t-s| for t-s in [D-63, D+15]; two 64-slots cover
    {
      int lo_ts = D - 63, hi_ts = D + 15;
      int alo = lo_ts < 0 ? -lo_ts : lo_ts;
      int ahi = hi_ts < 0 ? -hi_ts : hi_ts;
      int amax = alo > ahi ? alo : ahi;
      int amin = (lo_ts <= 0 && hi_ts >= 0) ? 0 : (alo < ahi ? alo : ahi);
      int jmin = 1023 - amax, jmax = 1023 - amin;
      int b0 = jmin & ~63;
      ensure(b0);
      if (jmax >= b0 + 64) ensure(b0 + 64);
    }

    // AC^T = K . qu^T : accac[g][r] = S[t=q15][s = s0+16g+4q4+r]
    f32x4 accac[4];
#pragma unroll
    for (int g = 0; g < 4; ++g) accac[g] = (f32x4){0.f, 0.f, 0.f, 0.f};
#pragma unroll
    for (int kc = 0; kc < 2; ++kc) {
      const int kof = kc * 32 + q4 * 8;
      bf16x8 kf[4];
#pragma unroll
      for (int g = 0; g < 4; ++g)
        kf[g] = *(const bf16x8*)(kB + (s0 + 16 * g + q15) * 64 + kof);
      __builtin_amdgcn_s_setprio(1);
#pragma unroll
      for (int g = 0; g < 4; ++g)
        accac[g] = __builtin_amdgcn_mfma_f32_16x16x32_bf16(kf[g], quf[kc], accac[g], 0, 0, 0);
      __builtin_amdgcn_s_setprio(0);
    }

    // scores + exp2 + pack P (l summed from same bf16 P via ones-MFMA)
    unsigned pk01[4], pk23[4];
    if (D >= 64) {
      // strictly below diagonal: j ascending with r
#pragma unroll
      for (int g = 0; g < 4; ++g) {
        int lo = 1023 - D - q15 + 16 * g + 4 * q4;
        int par = lo & 1, C = lo & ~1;
        unsigned w0 = *(const unsigned*)((char*)Bl + blrow + ((((C + 0) & 127) * 2) ^ rswz));
        unsigned w1 = *(const unsigned*)((char*)Bl + blrow + ((((C + 2) & 127) * 2) ^ rswz));
        unsigned w2 = *(const unsigned*)((char*)Bl + blrow + ((((C + 4) & 127) * 2) ^ rswz));
        unsigned u0 = par ? ((w1 << 16) | (w0 >> 16)) : w0;
        unsigned u1 = par ? ((w2 << 16) | (w1 >> 16)) : w1;
        float e0 = __builtin_amdgcn_exp2f(accac[g][0] + __uint_as_float(u0 << 16));
        float e1 = __builtin_amdgcn_exp2f(accac[g][1] + __uint_as_float(u0 & 0xFFFF0000u));
        float e2 = __builtin_amdgcn_exp2f(accac[g][2] + __uint_as_float(u1 << 16));
        float e3 = __builtin_amdgcn_exp2f(accac[g][3] + __uint_as_float(u1 & 0xFFFF0000u));
        pk01[g] = (__float_as_uint(e0) >> 16) | (__float_as_uint(e1) & 0xFFFF0000u);
        pk23[g] = (__float_as_uint(e2) >> 16) | (__float_as_uint(e3) & 0xFFFF0000u);
      }
    } else if (D <= -16) {
      // strictly above diagonal: j descending with r
#pragma unroll
      for (int g = 0; g < 4; ++g) {
        int lo = 1020 + D + q15 - 16 * g - 4 * q4;
        int par = lo & 1, C = lo & ~1;
        unsigned w0 = *(const unsigned*)((char*)Bl + blrow + ((((C + 0) & 127) * 2) ^ rswz));
        unsigned w1 = *(const unsigned*)((char*)Bl + blrow + ((((C + 2) & 127) * 2) ^ rswz));
        unsigned w2 = *(const unsigned*)((char*)Bl + blrow + ((((C + 4) & 127) * 2) ^ rswz));
        unsigned u0 = par ? ((w1 << 16) | (w0 >> 16)) : w0;
        unsigned u1 = par ? ((w2 << 16) | (w1 >> 16)) : w1;
        float e3 = __builtin_amdgcn_exp2f(accac[g][3] + __uint_as_float(u0 << 16));
        float e2 = __builtin_amdgcn_exp2f(accac[g][2] + __uint_as_float(u0 & 0xFFFF0000u));
        float e1 = __builtin_amdgcn_exp2f(accac[g][1] + __uint_as_float(u1 << 16));
        float e0 = __builtin_amdgcn_exp2f(accac[g][0] + __uint_as_float(u1 & 0xFFFF0000u));
        pk01[g] = (__float_as_uint(e0) >> 16) | (__float_as_uint(e1) & 0xFFFF0000u);
        pk23[g] = (__float_as_uint(e2) >> 16) | (__float_as_uint(e3) & 0xFFFF0000u);
      }
    } else {
      // straddles diagonal (one tile per wave): per-element |t-s|; single live slot 960
      const int e0c = D + q15 - 4 * q4;
#pragma unroll
      for (int g = 0; g < 4; ++g) {
        float ev[4];
#pragma unroll
        for (int r = 0; r < 4; ++r) {
          int e = e0c - 16 * g - r;
          int d = e < 0 ? -e : e;
          unsigned hv = *(const unsigned short*)((char*)Bl + blrow + ((((1023 - d) & 127) * 2) ^ rswz));
          ev[r] = __builtin_amdgcn_exp2f(accac[g][r] + __uint_as_float(hv << 16));
        }
        pk01[g] = (__float_as_uint(ev[0]) >> 16) | (__float_as_uint(ev[1]) & 0xFFFF0000u);
        pk23[g] = (__float_as_uint(ev[2]) >> 16) | (__float_as_uint(ev[3]) & 0xFFFF0000u);
      }
    }

    // P -> Pl: lane's 16 values all in row t=q15, 4 runs of 4 consecutive s-cols
#pragma unroll
    for (int g = 0; g < 4; ++g) {
      u32x2 pk; pk[0] = pk01[g]; pk[1] = pk23[g];
      int inrow = (16 * g + 4 * q4) * 2;
      *(u32x2*)((char*)Pl + plrow + (inrow ^ rswz)) = pk;
    }

    // O^T += V^T . P^T ; l += ones . P^T
#pragma unroll
    for (int kc = 0; kc < 2; ++kc) {
      const int kbyte = kc * 64 + q4 * 16;
      const int kof = kc * 32 + q4 * 8;
      bf16x8 pf = *(const bf16x8*)((char*)Pl + plrow + (kbyte ^ rswz));
      bf16x8 vf[4];
#pragma unroll
      for (int g = 0; g < 4; ++g)
        vf[g] = *(const bf16x8*)(vB + (16 * g + q15) * 1024 + s0 + kof);
      __builtin_amdgcn_s_setprio(1);
      accl = __builtin_amdgcn_mfma_f32_16x16x32_bf16(ones, pf, accl, 0, 0, 0);
#pragma unroll
      for (int g = 0; g < 4; ++g)
        acco[g] = __builtin_amdgcn_mfma_f32_16x16x32_bf16(vf[g], pf, acco[g], 0, 0, 0);
      __builtin_amdgcn_s_setprio(0);
    }
  }

  // outputs: acco[g][r] = O^T[dv=16g+4q4+r][t=q15]  -> float4 stores
  size_t obase = ((size_t)(sh * 2 + b) * 16 + h) * 1024;
  const int tt = tb + q15;
#pragma unroll
  for (int g = 0; g < 4; ++g)
    *(f32x4*)(Opart + (obase + tt) * 64 + 16 * g + 4 * q4) = acco[g];
  if (lane < 16) larr[obase + tt] = accl[0];
}

// ---------------- combine split-s halves ----------------
__global__ void combine_k(const float* __restrict__ O, const float* __restrict__ larr,
                          short* __restrict__ x)
{
  int i = blockIdx.x * 256 + threadIdx.x;
  int dv4 = i & 15, rest = i >> 4;
  float4 a0 = *(const float4*)(O + (size_t)rest * 64 + dv4 * 4);
  float4 a1 = *(const float4*)(O + 2097152 + (size_t)rest * 64 + dv4 * 4);
  float l0 = larr[rest], l1 = larr[32768 + rest];
  float inv = 1.0f / (l0 + l1);
  int bq = rest >> 14, hq = (rest >> 10) & 15, tq = rest & 1023;
  short4v o;
  o[0] = f2b((a0.x + a1.x) * inv);
  o[1] = f2b((a0.y + a1.y) * inv);
  o[2] = f2b((a0.z + a1.z) * inv);
  o[3] = f2b((a0.w + a1.w) * inv);
  *(short4v*)(x + ((size_t)(bq * 1024 + tq) * 1024 + hq * 64 + dv4 * 4)) = o;
}

// ---------------- launch ----------------
extern "C" void kernel_launch(void* const* d_in, const int* in_sizes, int n_in,
                              void* d_out, int out_size, void* d_ws, size_t ws_size,
                              hipStream_t stream) {
  const float* query = (const float*)d_in[0];
  const float* key   = (const float*)d_in[1];
  const float* value = (const float*)d_in[2];
  const float* pos   = (const float*)d_in[3];
  const float* Wq = (const float*)d_in[4];  const float* bq = (const float*)d_in[5];
  const float* Wk = (const float*)d_in[6];  const float* bk = (const float*)d_in[7];
  const float* Wv = (const float*)d_in[8];  const float* bv = (const float*)d_in[9];
  const float* Wp = (const float*)d_in[10]; const float* bp = (const float*)d_in[11];
  const float* Wo = (const float*)d_in[12]; const float* bo = (const float*)d_in[13];
  const float* ub = (const float*)d_in[14]; const float* vb = (const float*)d_in[15];

  char* ws = (char*)d_ws;
  const size_t MB = 1 << 20;
  short* Wo_bf    = (short*)(ws);            // 2MB
  short* qu_bf    = (short*)(ws + 2 * MB);   // 4MB
  short* qv_bf    = (short*)(ws + 6 * MB);   // 4MB
  short* k_bf     = (short*)(ws + 10 * MB);  // 4MB
  short* vT_bf    = (short*)(ws + 14 * MB);  // 4MB
  short* p_bf     = (short*)(ws + 18 * MB);  // 2MB
  short* x_bf     = (short*)(ws + 20 * MB);  // 4MB
  short* query_bf = (short*)(ws + 24 * MB);  // 4MB  (dead after gemm_qkvp)
  short* key_bf   = (short*)(ws + 28 * MB);  // 4MB
  short* value_bf = (short*)(ws + 32 * MB);  // 4MB
  short* pos_bf   = (short*)(ws + 36 * MB);  // 2MB
  short* Wq_bf    = (short*)(ws + 38 * MB);  // 2MB
  short* Wk_bf    = (short*)(ws + 40 * MB);  // 2MB
  short* Wv_bf    = (short*)(ws + 42 * MB);  // 2MB
  short* Wp_bf    = (short*)(ws + 44 * MB);  // 2MB -> 46MB total
  // aliases (written after their underlying buffers are dead)
  float* Opart = (float*)(ws + 24 * MB);     // 16MB over query/key/value/pos
  float* larr  = (float*)(ws + 40 * MB);     // 256KB over Wk_bf

  CvtTab tab;
  tab.s[0] = query;           tab.d[0] = query_bf;
  tab.s[1] = query + 1048576; tab.d[1] = query_bf + 1048576;
  tab.s[2] = key;             tab.d[2] = key_bf;
  tab.s[3] = key + 1048576;   tab.d[3] = key_bf + 1048576;
  tab.s[4] = value;           tab.d[4] = value_bf;
  tab.s[5] = value + 1048576; tab.d[5] = value_bf + 1048576;
  tab.s[6] = pos;             tab.d[6] = pos_bf;
  tab.s[7] = Wq;              tab.d[7] = Wq_bf;
  tab.s[8] = Wk;              tab.d[8] = Wk_bf;
  tab.s[9] = Wv;              tab.d[9] = Wv_bf;
  tab.s[10] = Wp;             tab.d[10] = Wp_bf;
  tab.s[11] = Wo;             tab.d[11] = Wo_bf;
  hipLaunchKernelGGL(cvt_all, dim3(12288), dim3(256), 0, stream, tab);

  hipLaunchKernelGGL(gemm_qkvp, dim3(448), dim3(256), 0, stream,
                     query_bf, key_bf, value_bf, pos_bf,
                     Wq_bf, Wk_bf, Wv_bf, Wp_bf,
                     bq, bk, bv, bp, ub, vb,
                     qu_bf, qv_bf, k_bf, vT_bf, p_bf);

  hipLaunchKernelGGL(attn_kernel, dim3(4096), dim3(64), 0, stream,
                     qu_bf, qv_bf, k_bf, vT_bf, p_bf, Opart, larr);

  hipLaunchKernelGGL(combine_k, dim3(2048), dim3(256), 0, stream,
                     Opart, larr, x_bf);

  hipLaunchKernelGGL(gemm_out, dim3(256), dim3(256), 0, stream,
                     x_bf, Wo_bf, bo, (float*)d_out);
}

// Round 7
// 168.942 us; speedup vs baseline: 1.0509x; 1.0509x over previous
//
#include <hip/hip_runtime.h>
#include <hip/hip_bf16.h>
#include <stdint.h>

typedef __attribute__((ext_vector_type(8))) short bf16x8;
typedef __attribute__((ext_vector_type(4))) float f32x4;
typedef __attribute__((ext_vector_type(4))) short short4v;
typedef __attribute__((ext_vector_type(2))) unsigned u32x2;

#define SCALE2 0.18033688011112042f  /* (1/8) * log2(e) */

__device__ __forceinline__ short f2b(float f) {
  union { float f; unsigned u; } un; un.f = f;
  unsigned r = un.u + 0x7FFFu + ((un.u >> 16) & 1u);
  return (short)(r >> 16);
}

// async global->LDS, 16B per lane; LDS dest is wave-uniform base + lane*16
#define GLDS(GP, LP) __builtin_amdgcn_global_load_lds( \
    (__attribute__((address_space(1))) void*)(GP), \
    (__attribute__((address_space(3))) void*)(LP), 16, 0, 0)

// ---------------- fused f32 -> bf16 conversion ----------------
struct CvtTab { const float* s[12]; short* d[12]; };

__global__ void cvt_all(CvtTab tab) {
  int chunk = blockIdx.x >> 10;
  int off = (blockIdx.x & 1023) * 256 + threadIdx.x;
  float4 v = *((const float4*)tab.s[chunk] + off);
  short4v o;
  o[0] = f2b(v.x); o[1] = f2b(v.y); o[2] = f2b(v.z); o[3] = f2b(v.w);
  *((short4v*)tab.d[chunk] + off) = o;
}

// ---------------- 128x128 bf16 GEMM core, K=1024, 2-phase dbuf ----------------
__device__ __forceinline__ void gemm_core128(
    const short* __restrict__ A, const short* __restrict__ W,
    int tile_m, int tile_n, short* lds, f32x4 acc[4][4])
{
  const int tid = threadIdx.x;
  const int wave = tid >> 6, lane = tid & 63;
  const int wr = wave >> 1, wc = wave & 1;
  const int q15 = lane & 15, q4 = lane >> 4;
  const int rl = lane >> 3;
  const int cswz = ((lane & 7) * 16) ^ (rl << 4);

#pragma unroll
  for (int i = 0; i < 4; ++i)
#pragma unroll
    for (int j = 0; j < 4; ++j) acc[i][j] = (f32x4){0.f, 0.f, 0.f, 0.f};

  auto stage = [&](int buf, int k0) {
    short* As = lds + buf * 16384;
    short* Bs = As + 8192;
#pragma unroll
    for (int s = 0; s < 4; ++s) {
      int ia = wave * 4 + s;
      int row = ia * 8 + rl;
      GLDS(A + (size_t)(tile_m + row) * 1024 + k0 + (cswz >> 1), (char*)As + ia * 1024);
      GLDS(W + (size_t)(tile_n + row) * 1024 + k0 + (cswz >> 1), (char*)Bs + ia * 1024);
    }
  };

  stage(0, 0);
  __syncthreads();
  for (int t = 0; t < 16; ++t) {
    const int cur = t & 1;
    if (t < 15) stage(cur ^ 1, (t + 1) * 64);
    const short* As = lds + cur * 16384;
    const short* Bs = As + 8192;
#pragma unroll
    for (int kk = 0; kk < 2; ++kk) {
      const int kbyte = kk * 64 + q4 * 16;
      const int rswz = (q15 & 7) << 4;
      bf16x8 af[4], bfr[4];
#pragma unroll
      for (int i = 0; i < 4; ++i)
        af[i] = *(const bf16x8*)((const char*)As + (wr * 64 + i * 16 + q15) * 128 + (kbyte ^ rswz));
#pragma unroll
      for (int j = 0; j < 4; ++j)
        bfr[j] = *(const bf16x8*)((const char*)Bs + (wc * 64 + j * 16 + q15) * 128 + (kbyte ^ rswz));
#pragma unroll
      for (int i = 0; i < 4; ++i)
#pragma unroll
        for (int j = 0; j < 4; ++j)
          acc[i][j] = __builtin_amdgcn_mfma_f32_16x16x32_bf16(af[i], bfr[j], acc[i][j], 0, 0, 0);
    }
    __syncthreads();
  }
}

// ---------------- stacked QKVP projection GEMM ----------------
__global__ __launch_bounds__(256)
void gemm_qkvp(const short* __restrict__ q_in, const short* __restrict__ k_in,
               const short* __restrict__ v_in, const short* __restrict__ p_in,
               const short* __restrict__ wq, const short* __restrict__ wk,
               const short* __restrict__ wv, const short* __restrict__ wp,
               const float* __restrict__ bq, const float* __restrict__ bk,
               const float* __restrict__ bv, const float* __restrict__ bp,
               const float* __restrict__ ub, const float* __restrict__ vb,
               short* __restrict__ qu, short* __restrict__ qv,
               short* __restrict__ kx, short* __restrict__ vtp, short* __restrict__ pp)
{
  __shared__ __align__(16) short lds[32768];
  const int n = blockIdx.x;
  const int by = n & 7;
  const int bx = n >> 3;
  const short* A; const short* W; const float* bias; int tm, mode;
  if (bx < 16)      { A = q_in; W = wq; bias = bq; tm = bx;      mode = 0; }
  else if (bx < 32) { A = k_in; W = wk; bias = bk; tm = bx - 16; mode = 1; }
  else if (bx < 48) { A = v_in; W = wv; bias = bv; tm = bx - 32; mode = 2; }
  else              { A = p_in; W = wp; bias = bp; tm = bx - 48; mode = 3; }

  f32x4 acc[4][4];
  gemm_core128(A, W, tm * 128, by * 128, lds, acc);

  const int lane = threadIdx.x & 63, wave = threadIdx.x >> 6;
  const int wr = wave >> 1, wc = wave & 1, q15 = lane & 15, q4 = lane >> 4;
#pragma unroll
  for (int i = 0; i < 4; ++i)
#pragma unroll
    for (int j = 0; j < 4; ++j)
#pragma unroll
      for (int r = 0; r < 4; ++r) {
        int m = tm * 128 + wr * 64 + i * 16 + q4 * 4 + r;
        int nn = by * 128 + wc * 64 + j * 16 + q15;
        float v = acc[i][j][r] + bias[nn];
        int bb = m >> 10, t = m & 1023, hh = nn >> 6, d = nn & 63;
        if (mode == 0) {
          size_t o = ((size_t)(bb * 16 + hh) * 1024 + t) * 64 + d;
          qu[o] = f2b((v + ub[nn]) * SCALE2);   // pre-scale: scores come out in log2 units
          qv[o] = f2b((v + vb[nn]) * SCALE2);
        } else if (mode == 1) {
          kx[((size_t)(bb * 16 + hh) * 1024 + t) * 64 + d] = f2b(v);
        } else if (mode == 2) {
          vtp[((size_t)(bb * 16 + hh) * 64 + d) * 1024 + t] = f2b(v);
        } else {
          pp[((size_t)hh * 1024 + m) * 64 + d] = f2b(v);
        }
      }
}

// ---------------- output GEMM, 128x64 tiles (256 blocks), f32 out ----------------
__global__ __launch_bounds__(256)
void gemm_out(const short* __restrict__ X, const short* __restrict__ W,
              const float* __restrict__ bo, float* __restrict__ out)
{
  __shared__ __align__(16) short lds[24576];
  const int n = blockIdx.x;
  const int bxm = (n >> 3) & 15;
  const int byn = ((n & 7) << 1) | (n >> 7);
  const int tile_m = bxm * 128, tile_n = byn * 64;

  const int tid = threadIdx.x;
  const int wave = tid >> 6, lane = tid & 63;
  const int wr = wave >> 1, wc = wave & 1;
  const int q15 = lane & 15, q4 = lane >> 4;
  const int rl = lane >> 3;
  const int cswz = ((lane & 7) * 16) ^ (rl << 4);

  f32x4 acc[4][2];
#pragma unroll
  for (int i = 0; i < 4; ++i)
#pragma unroll
    for (int j = 0; j < 2; ++j) acc[i][j] = (f32x4){0.f, 0.f, 0.f, 0.f};

  auto stage = [&](int buf, int k0) {
    short* As = lds + buf * 12288;
    short* Bs = As + 8192;
#pragma unroll
    for (int s = 0; s < 6; ++s) {
      int idx = wave * 6 + s;
      if (idx < 16) {
        int row = idx * 8 + rl;
        GLDS(X + (size_t)(tile_m + row) * 1024 + k0 + (cswz >> 1), (char*)As + idx * 1024);
      } else {
        int i2 = idx - 16;
        int row = i2 * 8 + rl;
        GLDS(W + (size_t)(tile_n + row) * 1024 + k0 + (cswz >> 1), (char*)Bs + i2 * 1024);
      }
    }
  };

  stage(0, 0);
  __syncthreads();
  for (int t = 0; t < 16; ++t) {
    const int cur = t & 1;
    if (t < 15) stage(cur ^ 1, (t + 1) * 64);
    const short* As = lds + cur * 12288;
    const short* Bs = As + 8192;
#pragma unroll
    for (int kk = 0; kk < 2; ++kk) {
      const int kbyte = kk * 64 + q4 * 16;
      const int rswz = (q15 & 7) << 4;
      bf16x8 af[4], bfr[2];
#pragma unroll
      for (int i = 0; i < 4; ++i)
        af[i] = *(const bf16x8*)((const char*)As + (wr * 64 + i * 16 + q15) * 128 + (kbyte ^ rswz));
#pragma unroll
      for (int j = 0; j < 2; ++j)
        bfr[j] = *(const bf16x8*)((const char*)Bs + (wc * 32 + j * 16 + q15) * 128 + (kbyte ^ rswz));
#pragma unroll
      for (int i = 0; i < 4; ++i)
#pragma unroll
        for (int j = 0; j < 2; ++j)
          acc[i][j] = __builtin_amdgcn_mfma_f32_16x16x32_bf16(af[i], bfr[j], acc[i][j], 0, 0, 0);
    }
    __syncthreads();
  }

#pragma unroll
  for (int i = 0; i < 4; ++i)
#pragma unroll
    for (int j = 0; j < 2; ++j)
#pragma unroll
      for (int r = 0; r < 4; ++r) {
        int m = tile_m + wr * 64 + i * 16 + q4 * 4 + r;
        int nn = tile_n + wc * 32 + j * 16 + q15;
        out[(size_t)m * 1024 + nn] = acc[i][j][r] + bo[nn];
      }
}

// ---------------- fused rel-pos flash attention ----------------
// 4 independent waves per block (no barriers); each wave owns 16 t-rows x 512 s.
// K/V fragments read direct from global (L2) with loads hoisted for latency hiding.
__global__ __launch_bounds__(256, 4)
void attn_kernel(const short* __restrict__ qu, const short* __restrict__ qv,
                 const short* __restrict__ kmat, const short* __restrict__ vt,
                 const short* __restrict__ p,
                 float* __restrict__ Opart, float* __restrict__ larr)
{
  __shared__ __align__(16) short Bl[8192];   // 4 waves x (16 t-rows x 128 j-cols), swizzled
  __shared__ __align__(16) short Pl[4096];   // 4 waves x (16 t-rows x 64 s-cols), swizzled

  const int tid = threadIdx.x;
  const int wave = tid >> 6, lane = tid & 63;

  // XCD swizzle on wave work-items: 512 consecutive per XCD; waves in a block
  // are consecutive items -> same (b,h,sh), shared K/V L2 lines
  const int nB = blockIdx.x;
  const int o = (nB & 7) * 512 + (nB >> 3) * 4 + wave;
  const int tb = (o & 63) * 16;        // t-row base
  const int h = (o >> 6) & 15;
  const int z = o >> 10;
  const int b = z >> 1, sh = z & 1;

  const int q15 = lane & 15, q4 = lane >> 4;
  const size_t bh = (size_t)(b * 16 + h);
  const short* pW = p + (size_t)h * 65536;
  const short* kB = kmat + bh * 65536;
  const short* vB = vt + bh * 65536;
  const int rswz = (q15 & 7) << 4;
  char* BlW = (char*)Bl + wave * 4096;
  char* PlW = (char*)Pl + wave * 2048;
  const int blrow = q15 * 256;
  const int plrow = q15 * 128;

  bf16x8 quf[2], qvf[2];
  {
    size_t base = (bh * 1024 + tb + q15) * 64 + q4 * 8;
    quf[0] = *(const bf16x8*)(qu + base);
    quf[1] = *(const bf16x8*)(qu + base + 32);
    qvf[0] = *(const bf16x8*)(qv + base);
    qvf[1] = *(const bf16x8*)(qv + base + 32);
  }
  bf16x8 ones;
#pragma unroll
  for (int i = 0; i < 8; ++i) ones[i] = (short)0x3F80;  // bf16 1.0

  f32x4 acco[4], accl;
#pragma unroll
  for (int g = 0; g < 4; ++g) acco[g] = (f32x4){0.f, 0.f, 0.f, 0.f};
  accl = (f32x4){0.f, 0.f, 0.f, 0.f};

  int live0 = -1, live1 = -1;

  // refill: BD window rows j in [base, base+64); lane holds j=base+16g+4q4+r at t-col q15
  auto refill = [&](int base) {
    f32x4 bacc[4];
#pragma unroll
    for (int g = 0; g < 4; ++g) bacc[g] = (f32x4){0.f, 0.f, 0.f, 0.f};
#pragma unroll
    for (int kc = 0; kc < 2; ++kc) {
      const int kof = kc * 32 + q4 * 8;
#pragma unroll
      for (int g = 0; g < 4; ++g) {
        bf16x8 pf = *(const bf16x8*)(pW + (size_t)(base + g * 16 + q15) * 64 + kof);
        bacc[g] = __builtin_amdgcn_mfma_f32_16x16x32_bf16(pf, qvf[kc], bacc[g], 0, 0, 0);
      }
    }
    const int pbase = base & 127;
#pragma unroll
    for (int g = 0; g < 4; ++g) {
      unsigned a0 = __float_as_uint(bacc[g][0]); a0 = a0 + 0x7FFFu + ((a0 >> 16) & 1u);
      unsigned a1 = __float_as_uint(bacc[g][1]); a1 = a1 + 0x7FFFu + ((a1 >> 16) & 1u);
      unsigned a2 = __float_as_uint(bacc[g][2]); a2 = a2 + 0x7FFFu + ((a2 >> 16) & 1u);
      unsigned a3 = __float_as_uint(bacc[g][3]); a3 = a3 + 0x7FFFu + ((a3 >> 16) & 1u);
      u32x2 pk;
      pk[0] = (a0 >> 16) | (a1 & 0xFFFF0000u);
      pk[1] = (a2 >> 16) | (a3 & 0xFFFF0000u);
      int inrow = (pbase + 16 * g + 4 * q4) * 2;
      *(u32x2*)(BlW + blrow + (inrow ^ rswz)) = pk;
    }
  };

  auto ensure = [&](int base) {
    if ((base >> 6) & 1) { if (live1 != base) { refill(base); live1 = base; } }
    else                 { if (live0 != base) { refill(base); live0 = base; } }
  };

  const int sbeg = sh * 512;
  for (int s0 = sbeg; s0 < sbeg + 512; s0 += 64) {
    const int D = tb - s0;   // t-s offset, multiple of 16

    // 1) issue all K-fragment loads for this tile (latency hides under refill)
    bf16x8 kf[2][4];
#pragma unroll
    for (int kc = 0; kc < 2; ++kc)
#pragma unroll
      for (int g = 0; g < 4; ++g)
        kf[kc][g] = *(const bf16x8*)(kB + (s0 + 16 * g + q15) * 64 + kc * 32 + q4 * 8);

    // 2) window maintenance: j = 1023-|t-s| for t-s in [D-63, D+15]; two 64-slots cover
    {
      int lo_ts = D - 63, hi_ts = D + 15;
      int alo = lo_ts < 0 ? -lo_ts : lo_ts;
      int ahi = hi_ts < 0 ? -hi_ts : hi_ts;
      int amax = alo > ahi ? alo : ahi;
      int amin = (lo_ts <= 0 && hi_ts >= 0) ? 0 : (alo < ahi ? alo : ahi);
      int jmin = 1023 - amax, jmax = 1023 - amin;
      int b0 = jmin & ~63;
      ensure(b0);
      if (jmax >= b0 + 64) ensure(b0 + 64);
    }

    // 3) AC^T = K . qu^T : accac[g][r] = S[t=q15][s = s0+16g+4q4+r]
    f32x4 accac[4];
#pragma unroll
    for (int g = 0; g < 4; ++g) accac[g] = (f32x4){0.f, 0.f, 0.f, 0.f};
    __builtin_amdgcn_s_setprio(1);
#pragma unroll
    for (int kc = 0; kc < 2; ++kc)
#pragma unroll
      for (int g = 0; g < 4; ++g)
        accac[g] = __builtin_amdgcn_mfma_f32_16x16x32_bf16(kf[kc][g], quf[kc], accac[g], 0, 0, 0);
    __builtin_amdgcn_s_setprio(0);

    // 4) issue all V-fragment loads (latency hides under score phase)
    bf16x8 vf[2][4];
#pragma unroll
    for (int kc = 0; kc < 2; ++kc)
#pragma unroll
      for (int g = 0; g < 4; ++g)
        vf[kc][g] = *(const bf16x8*)(vB + (16 * g + q15) * 1024 + s0 + kc * 32 + q4 * 8);

    // 5) scores + exp2 + pack P (l summed from same bf16 P via ones-MFMA)
    unsigned pk01[4], pk23[4];
    if (D >= 64) {
      // strictly below diagonal: j ascending with r
#pragma unroll
      for (int g = 0; g < 4; ++g) {
        int lo = 1023 - D - q15 + 16 * g + 4 * q4;
        int par = lo & 1, C = lo & ~1;
        unsigned w0 = *(const unsigned*)(BlW + blrow + ((((C + 0) & 127) * 2) ^ rswz));
        unsigned w1 = *(const unsigned*)(BlW + blrow + ((((C + 2) & 127) * 2) ^ rswz));
        unsigned w2 = *(const unsigned*)(BlW + blrow + ((((C + 4) & 127) * 2) ^ rswz));
        unsigned u0 = par ? ((w1 << 16) | (w0 >> 16)) : w0;
        unsigned u1 = par ? ((w2 << 16) | (w1 >> 16)) : w1;
        float e0 = __builtin_amdgcn_exp2f(accac[g][0] + __uint_as_float(u0 << 16));
        float e1 = __builtin_amdgcn_exp2f(accac[g][1] + __uint_as_float(u0 & 0xFFFF0000u));
        float e2 = __builtin_amdgcn_exp2f(accac[g][2] + __uint_as_float(u1 << 16));
        float e3 = __builtin_amdgcn_exp2f(accac[g][3] + __uint_as_float(u1 & 0xFFFF0000u));
        pk01[g] = (__float_as_uint(e0) >> 16) | (__float_as_uint(e1) & 0xFFFF0000u);
        pk23[g] = (__float_as_uint(e2) >> 16) | (__float_as_uint(e3) & 0xFFFF0000u);
      }
    } else if (D <= -16) {
      // strictly above diagonal: j descending with r
#pragma unroll
      for (int g = 0; g < 4; ++g) {
        int lo = 1020 + D + q15 - 16 * g - 4 * q4;
        int par = lo & 1, C = lo & ~1;
        unsigned w0 = *(const unsigned*)(BlW + blrow + ((((C + 0) & 127) * 2) ^ rswz));
        unsigned w1 = *(const unsigned*)(BlW + blrow + ((((C + 2) & 127) * 2) ^ rswz));
        unsigned w2 = *(const unsigned*)(BlW + blrow + ((((C + 4) & 127) * 2) ^ rswz));
        unsigned u0 = par ? ((w1 << 16) | (w0 >> 16)) : w0;
        unsigned u1 = par ? ((w2 << 16) | (w1 >> 16)) : w1;
        float e3 = __builtin_amdgcn_exp2f(accac[g][3] + __uint_as_float(u0 << 16));
        float e2 = __builtin_amdgcn_exp2f(accac[g][2] + __uint_as_float(u0 & 0xFFFF0000u));
        float e1 = __builtin_amdgcn_exp2f(accac[g][1] + __uint_as_float(u1 << 16));
        float e0 = __builtin_amdgcn_exp2f(accac[g][0] + __uint_as_float(u1 & 0xFFFF0000u));
        pk01[g] = (__float_as_uint(e0) >> 16) | (__float_as_uint(e1) & 0xFFFF0000u);
        pk23[g] = (__float_as_uint(e2) >> 16) | (__float_as_uint(e3) & 0xFFFF0000u);
      }
    } else {
      // straddles diagonal: per-element |t-s|; live slot base 960
      const int e0c = D + q15 - 4 * q4;
#pragma unroll
      for (int g = 0; g < 4; ++g) {
        float ev[4];
#pragma unroll
        for (int r = 0; r < 4; ++r) {
          int e = e0c - 16 * g - r;
          int d = e < 0 ? -e : e;
          unsigned hv = *(const unsigned short*)(BlW + blrow + ((((1023 - d) & 127) * 2) ^ rswz));
          ev[r] = __builtin_amdgcn_exp2f(accac[g][r] + __uint_as_float(hv << 16));
        }
        pk01[g] = (__float_as_uint(ev[0]) >> 16) | (__float_as_uint(ev[1]) & 0xFFFF0000u);
        pk23[g] = (__float_as_uint(ev[2]) >> 16) | (__float_as_uint(ev[3]) & 0xFFFF0000u);
      }
    }

    // P -> Pl: lane's 16 values all in row t=q15, 4 runs of 4 consecutive s-cols
#pragma unroll
    for (int g = 0; g < 4; ++g) {
      u32x2 pk; pk[0] = pk01[g]; pk[1] = pk23[g];
      int inrow = (16 * g + 4 * q4) * 2;
      *(u32x2*)(PlW + plrow + (inrow ^ rswz)) = pk;
    }

    // 6) O^T += V^T . P^T ; l += ones . P^T
#pragma unroll
    for (int kc = 0; kc < 2; ++kc) {
      const int kbyte = kc * 64 + q4 * 16;
      bf16x8 pf = *(const bf16x8*)(PlW + plrow + (kbyte ^ rswz));
      __builtin_amdgcn_s_setprio(1);
      accl = __builtin_amdgcn_mfma_f32_16x16x32_bf16(ones, pf, accl, 0, 0, 0);
#pragma unroll
      for (int g = 0; g < 4; ++g)
        acco[g] = __builtin_amdgcn_mfma_f32_16x16x32_bf16(vf[kc][g], pf, acco[g], 0, 0, 0);
      __builtin_amdgcn_s_setprio(0);
    }
  }

  // outputs: acco[g][r] = O^T[dv=16g+4q4+r][t=q15]  -> float4 stores
  size_t obase = ((size_t)(sh * 2 + b) * 16 + h) * 1024;
  const int tt = tb + q15;
#pragma unroll
  for (int g = 0; g < 4; ++g)
    *(f32x4*)(Opart + (obase + tt) * 64 + 16 * g + 4 * q4) = acco[g];
  if (lane < 16) larr[obase + tt] = accl[0];
}

// ---------------- combine split-s halves ----------------
__global__ void combine_k(const float* __restrict__ O, const float* __restrict__ larr,
                          short* __restrict__ x)
{
  int i = blockIdx.x * 256 + threadIdx.x;
  int dv4 = i & 15, rest = i >> 4;
  float4 a0 = *(const float4*)(O + (size_t)rest * 64 + dv4 * 4);
  float4 a1 = *(const float4*)(O + 2097152 + (size_t)rest * 64 + dv4 * 4);
  float l0 = larr[rest], l1 = larr[32768 + rest];
  float inv = 1.0f / (l0 + l1);
  int bq = rest >> 14, hq = (rest >> 10) & 15, tq = rest & 1023;
  short4v o;
  o[0] = f2b((a0.x + a1.x) * inv);
  o[1] = f2b((a0.y + a1.y) * inv);
  o[2] = f2b((a0.z + a1.z) * inv);
  o[3] = f2b((a0.w + a1.w) * inv);
  *(short4v*)(x + ((size_t)(bq * 1024 + tq) * 1024 + hq * 64 + dv4 * 4)) = o;
}

// ---------------- launch ----------------
extern "C" void kernel_launch(void* const* d_in, const int* in_sizes, int n_in,
                              void* d_out, int out_size, void* d_ws, size_t ws_size,
                              hipStream_t stream) {
  const float* query = (const float*)d_in[0];
  const float* key   = (const float*)d_in[1];
  const float* value = (const float*)d_in[2];
  const float* pos   = (const float*)d_in[3];
  const float* Wq = (const float*)d_in[4];  const float* bq = (const float*)d_in[5];
  const float* Wk = (const float*)d_in[6];  const float* bk = (const float*)d_in[7];
  const float* Wv = (const float*)d_in[8];  const float* bv = (const float*)d_in[9];
  const float* Wp = (const float*)d_in[10]; const float* bp = (const float*)d_in[11];
  const float* Wo = (const float*)d_in[12]; const float* bo = (const float*)d_in[13];
  const float* ub = (const float*)d_in[14]; const float* vb = (const float*)d_in[15];

  char* ws = (char*)d_ws;
  const size_t MB = 1 << 20;
  short* Wo_bf    = (short*)(ws);            // 2MB
  short* qu_bf    = (short*)(ws + 2 * MB);   // 4MB
  short* qv_bf    = (short*)(ws + 6 * MB);   // 4MB
  short* k_bf     = (short*)(ws + 10 * MB);  // 4MB
  short* vT_bf    = (short*)(ws + 14 * MB);  // 4MB
  short* p_bf     = (short*)(ws + 18 * MB);  // 2MB
  short* x_bf     = (short*)(ws + 20 * MB);  // 4MB
  short* query_bf = (short*)(ws + 24 * MB);  // 4MB  (dead after gemm_qkvp)
  short* key_bf   = (short*)(ws + 28 * MB);  // 4MB
  short* value_bf = (short*)(ws + 32 * MB);  // 4MB
  short* pos_bf   = (short*)(ws + 36 * MB);  // 2MB
  short* Wq_bf    = (short*)(ws + 38 * MB);  // 2MB
  short* Wk_bf    = (short*)(ws + 40 * MB);  // 2MB
  short* Wv_bf    = (short*)(ws + 42 * MB);  // 2MB
  short* Wp_bf    = (short*)(ws + 44 * MB);  // 2MB -> 46MB total
  // aliases (written after their underlying buffers are dead)
  float* Opart = (float*)(ws + 24 * MB);     // 16MB over query/key/value/pos
  float* larr  = (float*)(ws + 40 * MB);     // 256KB over Wk_bf

  CvtTab tab;
  tab.s[0] = query;           tab.d[0] = query_bf;
  tab.s[1] = query + 1048576; tab.d[1] = query_bf + 1048576;
  tab.s[2] = key;             tab.d[2] = key_bf;
  tab.s[3] = key + 1048576;   tab.d[3] = key_bf + 1048576;
  tab.s[4] = value;           tab.d[4] = value_bf;
  tab.s[5] = value + 1048576; tab.d[5] = value_bf + 1048576;
  tab.s[6] = pos;             tab.d[6] = pos_bf;
  tab.s[7] = Wq;              tab.d[7] = Wq_bf;
  tab.s[8] = Wk;              tab.d[8] = Wk_bf;
  tab.s[9] = Wv;              tab.d[9] = Wv_bf;
  tab.s[10] = Wp;             tab.d[10] = Wp_bf;
  tab.s[11] = Wo;             tab.d[11] = Wo_bf;
  hipLaunchKernelGGL(cvt_all, dim3(12288), dim3(256), 0, stream, tab);

  hipLaunchKernelGGL(gemm_qkvp, dim3(448), dim3(256), 0, stream,
                     query_bf, key_bf, value_bf, pos_bf,
                     Wq_bf, Wk_bf, Wv_bf, Wp_bf,
                     bq, bk, bv, bp, ub, vb,
                     qu_bf, qv_bf, k_bf, vT_bf, p_bf);

  hipLaunchKernelGGL(attn_kernel, dim3(1024), dim3(256), 0, stream,
                     qu_bf, qv_bf, k_bf, vT_bf, p_bf, Opart, larr);

  hipLaunchKernelGGL(combine_k, dim3(2048), dim3(256), 0, stream,
                     Opart, larr, x_bf);

  hipLaunchKernelGGL(gemm_out, dim3(256), dim3(256), 0, stream,
                     x_bf, Wo_bf, bo, (float*)d_out);
}